// Round 1
// baseline (106.936 us; speedup 1.0000x reference)
//
#include <hip/hip_runtime.h>

#define NM 64
#define NC 10
// ws layout: [0 .. NM*NC) = M[m*NC+c], [NM*NC .. NM*NC+NC) = c0[c]

__global__ __launch_bounds__(640) void cv2d_precompute(
    const float* __restrict__ S,     // [2N,2N] row-major, 2N=128
    const float* __restrict__ d,     // [128]
    const float* __restrict__ bias,  // [64]
    const float* __restrict__ W,     // [10,64]
    const float* __restrict__ bvec,  // [10]
    float* __restrict__ ws)
{
    const int t = threadIdx.x;
    const int twoN = 2 * NM;
    if (t < NM * NC) {
        const int m = t / NC;
        const int c = t - m * NC;
        float acc = 0.f;
        #pragma unroll
        for (int k = 0; k < NM; ++k) {
            // A[k][m] = S[2k, 2m];  M[m][c] = sum_k A[k][m] * W[c][k]
            acc += S[(2 * k) * twoN + 2 * m] * W[c * NM + k];
        }
        ws[m * NC + c] = acc;
    }
    if (t < NC) {
        float acc = bvec[t];
        #pragma unroll
        for (int k = 0; k < NM; ++k) {
            acc += (d[2 * k] + bias[k]) * W[t * NM + k];
        }
        ws[NM * NC + t] = acc;
    }
}

__global__ __launch_bounds__(256) void cv2d_main(
    const float* __restrict__ x,   // [B, 64]
    const float* __restrict__ Mc,  // ws: M[64*10] then c0[10]
    float* __restrict__ out,       // [B, 10]
    int Bn)
{
    const int row = blockIdx.x * 256 + threadIdx.x;
    if (row >= Bn) return;

    const float4* __restrict__ xr = (const float4*)(x + (size_t)row * NM);

    float acc[NC];
    #pragma unroll
    for (int c = 0; c < NC; ++c) acc[c] = Mc[NM * NC + c];

    #pragma unroll
    for (int q = 0; q < NM / 4; ++q) {
        const float4 v = xr[q];
        #pragma unroll
        for (int c = 0; c < NC; ++c) {
            // All Mc offsets are compile-time constants -> wave-uniform loads
            // -> s_load into SGPR; v_fmac_f32 takes the SGPR operand for free.
            acc[c] += v.x * Mc[(4 * q + 0) * NC + c];
            acc[c] += v.y * Mc[(4 * q + 1) * NC + c];
            acc[c] += v.z * Mc[(4 * q + 2) * NC + c];
            acc[c] += v.w * Mc[(4 * q + 3) * NC + c];
        }
    }

    // 10 floats = 40 B per row: 8-byte aligned always -> use float2 stores.
    float2* __restrict__ o = (float2*)(out + (size_t)row * NC);
    #pragma unroll
    for (int c = 0; c < NC; c += 2) {
        o[c / 2] = make_float2(acc[c], acc[c + 1]);
    }
}

extern "C" void kernel_launch(void* const* d_in, const int* in_sizes, int n_in,
                              void* d_out, int out_size, void* d_ws, size_t ws_size,
                              hipStream_t stream) {
    const float* x    = (const float*)d_in[0];
    const float* S    = (const float*)d_in[1];
    const float* d    = (const float*)d_in[2];
    const float* bias = (const float*)d_in[3];
    const float* W    = (const float*)d_in[4];
    const float* bvec = (const float*)d_in[5];
    float* out = (float*)d_out;
    float* ws  = (float*)d_ws;

    const int Bn = in_sizes[0] / NM;  // 200000

    cv2d_precompute<<<1, 640, 0, stream>>>(S, d, bias, W, bvec, ws);

    const int grid = (Bn + 255) / 256;
    cv2d_main<<<grid, 256, 0, stream>>>(x, ws, out, Bn);
}